// Round 10
// baseline (357.170 us; speedup 1.0000x reference)
//
#include <hip/hip_runtime.h>
#include <stdint.h>

typedef __bf16 bf16x8 __attribute__((ext_vector_type(8)));
typedef __bf16 bf16x4 __attribute__((ext_vector_type(4)));
typedef float  f32x4  __attribute__((ext_vector_type(4)));

// ---------------- unpool (feats stored bf16) ----------------
__global__ void k_up_f2b(const float4* __restrict__ xin, const int* __restrict__ up,
                         __bf16* __restrict__ xout, int N, int rowF4, int rowC) {
  int i = blockIdx.x * 256 + threadIdx.x;
  if (i >= N * rowF4) return;
  int n = i / rowF4, j = i - n * rowF4;
  float4 v = xin[(size_t)up[n] * rowF4 + j];
  bf16x4 o = {(__bf16)v.x, (__bf16)v.y, (__bf16)v.z, (__bf16)v.w};
  *reinterpret_cast<bf16x4*>(xout + (size_t)n * rowC + j * 4) = o;
}

__global__ void k_up_b2b(const uint4* __restrict__ xin, const int* __restrict__ up,
                         uint4* __restrict__ xout, int N, int rowU4) {
  int i = blockIdx.x * 256 + threadIdx.x;
  if (i >= N * rowU4) return;
  int n = i / rowU4, j = i - n * rowU4;
  xout[i] = xin[(size_t)up[n] * rowU4 + j];
}

// ================= bucket-partitioned CSR build (no global random scatter) =============
__global__ __launch_bounds__(256) void k_bhist(const int* __restrict__ dst, int E,
                                               int* __restrict__ bcnt, int nbk) {
  __shared__ int h[256];
  int t = threadIdx.x;
  h[t] = 0;
  __syncthreads();
  int e0 = blockIdx.x * 2048 + t * 8;
  if (e0 + 8 <= E) {
    int4 a = *reinterpret_cast<const int4*>(dst + e0);
    int4 b = *reinterpret_cast<const int4*>(dst + e0 + 4);
    atomicAdd(&h[a.x >> 10], 1); atomicAdd(&h[a.y >> 10], 1);
    atomicAdd(&h[a.z >> 10], 1); atomicAdd(&h[a.w >> 10], 1);
    atomicAdd(&h[b.x >> 10], 1); atomicAdd(&h[b.y >> 10], 1);
    atomicAdd(&h[b.z >> 10], 1); atomicAdd(&h[b.w >> 10], 1);
  } else {
    for (int j = 0; j < 8; ++j)
      if (e0 + j < E) atomicAdd(&h[dst[e0 + j] >> 10], 1);
  }
  __syncthreads();
  if (t < nbk && h[t]) atomicAdd(&bcnt[t], h[t]);
}

__global__ void k_bscan(const int* __restrict__ bcnt, int nbk, int E,
                        int* __restrict__ bstart, int* __restrict__ bcur) {
  __shared__ int wsum[4];
  int t = threadIdx.x, lane = t & 63, w = t >> 6;
  int v = (t < nbk) ? bcnt[t] : 0;
  int x = v;
  #pragma unroll
  for (int o = 1; o < 64; o <<= 1) { int y = __shfl_up(x, o, 64); if (lane >= o) x += y; }
  if (lane == 63) wsum[w] = x;
  __syncthreads();
  int wpre = 0;
  #pragma unroll
  for (int k = 0; k < 4; ++k) if (k < w) wpre += wsum[k];
  int excl = wpre + x - v;
  if (t < nbk) { bstart[t] = excl; bcur[t] = excl; }
  if (t == 0) bstart[nbk] = E;
}

__global__ __launch_bounds__(256) void k_bpart(const int* __restrict__ src,
                        const int* __restrict__ dst, const float2* __restrict__ pse,
                        int E, int* __restrict__ bcur, uint2* __restrict__ ebuf, int nbk) {
  __shared__ int h[256];
  __shared__ int base[256];
  int t = threadIdx.x;
  h[t] = 0;
  __syncthreads();
  int e0 = blockIdx.x * 2048 + t * 8;
  int d[8], rank[8];
  bool full = (e0 + 8 <= E);
  if (full) {
    int4 a = *reinterpret_cast<const int4*>(dst + e0);
    int4 b = *reinterpret_cast<const int4*>(dst + e0 + 4);
    d[0] = a.x; d[1] = a.y; d[2] = a.z; d[3] = a.w;
    d[4] = b.x; d[5] = b.y; d[6] = b.z; d[7] = b.w;
    #pragma unroll
    for (int j = 0; j < 8; ++j) rank[j] = atomicAdd(&h[d[j] >> 10], 1);
  } else {
    #pragma unroll
    for (int j = 0; j < 8; ++j)
      if (e0 + j < E) { d[j] = dst[e0 + j]; rank[j] = atomicAdd(&h[d[j] >> 10], 1); }
  }
  __syncthreads();
  if (t < nbk && h[t]) base[t] = atomicAdd(&bcur[t], h[t]);
  __syncthreads();
  if (full) {
    int4 a = *reinterpret_cast<const int4*>(src + e0);
    int4 b = *reinterpret_cast<const int4*>(src + e0 + 4);
    int s[8] = {a.x, a.y, a.z, a.w, b.x, b.y, b.z, b.w};
    float2 p[8];
    #pragma unroll
    for (int j = 0; j < 8; ++j) p[j] = pse[e0 + j];
    #pragma unroll
    for (int j = 0; j < 8; ++j) {
      int bkt = d[j] >> 10, dloc = d[j] & 1023;
      union { uint u; _Float16 hh[2]; } cv;
      cv.hh[0] = (_Float16)p[j].x; cv.hh[1] = (_Float16)p[j].y;
      ebuf[base[bkt] + rank[j]] = make_uint2((uint)s[j] | ((uint)dloc << 18), cv.u);
    }
  } else {
    #pragma unroll
    for (int j = 0; j < 8; ++j) {
      if (e0 + j >= E) continue;
      int bkt = d[j] >> 10, dloc = d[j] & 1023;
      float2 p = pse[e0 + j];
      union { uint u; _Float16 hh[2]; } cv;
      cv.hh[0] = (_Float16)p.x; cv.hh[1] = (_Float16)p.y;
      ebuf[base[bkt] + rank[j]] = make_uint2((uint)src[e0 + j] | ((uint)dloc << 18), cv.u);
    }
  }
}

__global__ __launch_bounds__(256) void k_bcsr(const int* __restrict__ bstart,
                        const uint2* __restrict__ ebuf, uint2* __restrict__ epk,
                        int* __restrict__ off, int N, int E, int nbk) {
  __shared__ int cnt[1024];
  __shared__ int excl[1024];
  __shared__ int cur[1024];
  __shared__ int wsum[4];
  int b = blockIdx.x, t = threadIdx.x;
  int e0 = bstart[b], e1 = bstart[b + 1];
  #pragma unroll
  for (int k = 0; k < 4; ++k) { cnt[t * 4 + k] = 0; cur[t * 4 + k] = 0; }
  __syncthreads();
  for (int i = e0 + t; i < e1; i += 256)
    atomicAdd(&cnt[(ebuf[i].x >> 18) & 1023], 1);
  __syncthreads();
  int lane = t & 63, w = t >> 6;
  int i0 = t * 4;
  int c0 = cnt[i0], c1 = cnt[i0 + 1], c2 = cnt[i0 + 2], c3 = cnt[i0 + 3];
  int s = c0 + c1 + c2 + c3, x = s;
  #pragma unroll
  for (int o = 1; o < 64; o <<= 1) { int y = __shfl_up(x, o, 64); if (lane >= o) x += y; }
  if (lane == 63) wsum[w] = x;
  __syncthreads();
  int wpre = 0;
  #pragma unroll
  for (int k = 0; k < 4; ++k) if (k < w) wpre += wsum[k];
  int ex = wpre + x - s;
  excl[i0] = ex; excl[i0 + 1] = ex + c0; excl[i0 + 2] = ex + c0 + c1; excl[i0 + 3] = ex + c0 + c1 + c2;
  int dg0 = b * 1024;
  int exv[4] = {ex, ex + c0, ex + c0 + c1, ex + c0 + c1 + c2};
  #pragma unroll
  for (int k = 0; k < 4; ++k) {
    int d = dg0 + i0 + k;
    if (d < N) off[d] = e0 + exv[k];
  }
  __syncthreads();
  for (int i = e0 + t; i < e1; i += 256) {
    uint2 r = ebuf[i];
    int dloc = (r.x >> 18) & 1023;
    int rk = atomicAdd(&cur[dloc], 1);
    epk[e0 + excl[dloc] + rk] = make_uint2(r.x & 0x3FFFFu, r.y);
  }
  if (b == nbk - 1 && t == 0) off[N] = E;
}

// ---------------- pack [W;R] -> bf16 MFMA B-fragments (all 4 convs, one launch) -------
__global__ void k_packall(const float* __restrict__ W1a, const float* __restrict__ R1a,
                          const float* __restrict__ W2a, const float* __restrict__ R2a,
                          const float* __restrict__ W1b, const float* __restrict__ R1b,
                          const float* __restrict__ W2b, const float* __restrict__ R2b,
                          __bf16* __restrict__ BpA, __bf16* __restrict__ BpB,
                          __bf16* __restrict__ BpC, __bf16* __restrict__ BpD) {
  int o = blockIdx.x * 256 + threadIdx.x;
  const float *W, *R; __bf16* Bp; int Cin, Cout;
  if (o < 20480)      { W = W1a; R = R1a; Bp = BpA; Cin = 64; Cout = 32; }
  else if (o < 30720) { W = W2a; R = R2a; Bp = BpB; Cin = 32; Cout = 32; o -= 20480; }
  else if (o < 35840) { W = W1b; R = R1b; Bp = BpC; Cin = 32; Cout = 16; o -= 30720; }
  else if (o < 38400) { W = W2b; R = R2b; Bp = BpD; Cin = 16; Cout = 16; o -= 35840; }
  else return;
  int CT = Cout / 16;
  int j = o & 7, lane = (o >> 3) & 63, tile = o >> 9;
  int ct = tile % CT, kc = tile / CT;
  int k = kc * 32 + ((lane >> 4) * 8) + j;
  int n = ct * 16 + (lane & 15);
  float v;
  if (k < 9 * Cin) { int k9 = k / Cin, cin = k - k9 * Cin; v = W[(k9 * Cin + cin) * Cout + n]; }
  else             { v = R[(k - 9 * Cin) * Cout + n]; }
  Bp[o] = (__bf16)v;
}

// -------- fused spline conv: chunk-4 prefetched edge loop -> LDS -> MFMA -----
// CPL=4 channels/lane; LPD=Cin/4 lanes/dst; DPB=256/LPD dsts/block.
// (256,6): cap ~85 VGPR -> 6 blocks/CU (24 waves) vs R9's (256,4)=16 waves.
// HAS_SKIP fuses the skip-concat (fp32 skip -> bf16 cols [Cout,2*Cout)) into the epilogue.
template<int Cin, int Cout, bool OUTF32, bool HAS_SKIP>
__global__ __launch_bounds__(256, 6) void k_conv(const int* __restrict__ off,
                        const uint2* __restrict__ epk,
                        const __bf16* __restrict__ X, const __bf16* __restrict__ Bp,
                        const float* __restrict__ bias, const float* __restrict__ skip,
                        void* __restrict__ outv, int N, int outStride) {
  constexpr int LPD = Cin / 4;      // lanes per dst: 4/8/16
  constexpr int DPB = 256 / LPD;    // dsts per block: 64/32/16
  constexpr int K   = 10 * Cin;     // 160/320/640
  constexpr int KP2 = K + 8;        // LDS row stride
  constexpr int NT  = DPB / 16;     // MFMA row-tiles per block
  constexpr int KC  = K / 32;
  constexpr int CT  = Cout / 16;
  constexpr int UNITS = NT * CT;

  __shared__ __bf16 As[DPB * KP2];

  int t = threadIdx.x;
  int g = t / LPD, sub = t % LPD;
  int d = blockIdx.x * DPB + g;

  float acc[9][4];
  #pragma unroll
  for (int k = 0; k < 9; ++k)
    #pragma unroll
    for (int v = 0; v < 4; ++v) acc[k][v] = 0.f;
  bf16x4 xd = {};

  if (d < N) {
    xd = *reinterpret_cast<const bf16x4*>(X + (size_t)d * Cin + sub * 4);
    int b0 = off[d], b1 = off[d + 1];
    int i = b0;
    for (; i + 4 <= b1; i += 4) {
      uint2 e0 = epk[i], e1 = epk[i + 1], e2 = epk[i + 2], e3 = epk[i + 3];
      bf16x4 xf0 = *reinterpret_cast<const bf16x4*>(X + (size_t)e0.x * Cin + sub * 4);
      bf16x4 xf1 = *reinterpret_cast<const bf16x4*>(X + (size_t)e1.x * Cin + sub * 4);
      bf16x4 xf2 = *reinterpret_cast<const bf16x4*>(X + (size_t)e2.x * Cin + sub * 4);
      bf16x4 xf3 = *reinterpret_cast<const bf16x4*>(X + (size_t)e3.x * Cin + sub * 4);
      uint ps[4] = {e0.y, e1.y, e2.y, e3.y};
      bf16x4 xfs[4] = {xf0, xf1, xf2, xf3};
      #pragma unroll
      for (int c = 0; c < 4; ++c) {
        union { uint u; _Float16 h[2]; } cv; cv.u = ps[c];
        float t0 = (float)cv.h[0], t1 = (float)cv.h[1];
        float u0 = 1.f - t0;
        float wi[3] = {0.5f * u0 * u0, -t0 * t0 + t0 + 0.5f, 0.5f * t0 * t0};
        float u1 = 1.f - t1;
        float wj[3] = {0.5f * u1 * u1, -t1 * t1 + t1 + 0.5f, 0.5f * t1 * t1};
        float xfv[4];
        #pragma unroll
        for (int v = 0; v < 4; ++v) xfv[v] = (float)xfs[c][v];
        #pragma unroll
        for (int ki = 0; ki < 3; ++ki)
          #pragma unroll
          for (int kj = 0; kj < 3; ++kj) {
            float w = wi[ki] * wj[kj];
            #pragma unroll
            for (int v = 0; v < 4; ++v)
              acc[ki * 3 + kj][v] += w * xfv[v];
          }
      }
    }
    for (; i < b1; ++i) {
      uint2 ep = epk[i];
      bf16x4 xf = *reinterpret_cast<const bf16x4*>(X + (size_t)ep.x * Cin + sub * 4);
      union { uint u; _Float16 h[2]; } cv; cv.u = ep.y;
      float t0 = (float)cv.h[0], t1 = (float)cv.h[1];
      float u0 = 1.f - t0;
      float wi[3] = {0.5f * u0 * u0, -t0 * t0 + t0 + 0.5f, 0.5f * t0 * t0};
      float u1 = 1.f - t1;
      float wj[3] = {0.5f * u1 * u1, -t1 * t1 + t1 + 0.5f, 0.5f * t1 * t1};
      float xfv[4];
      #pragma unroll
      for (int v = 0; v < 4; ++v) xfv[v] = (float)xf[v];
      #pragma unroll
      for (int ki = 0; ki < 3; ++ki)
        #pragma unroll
        for (int kj = 0; kj < 3; ++kj) {
          float w = wi[ki] * wj[kj];
          #pragma unroll
          for (int v = 0; v < 4; ++v)
            acc[ki * 3 + kj][v] += w * xfv[v];
        }
    }
  }

  __bf16* row = As + (size_t)g * KP2;
  #pragma unroll
  for (int k = 0; k < 9; ++k) {
    bf16x4 tmp;
    #pragma unroll
    for (int v = 0; v < 4; ++v) tmp[v] = (__bf16)acc[k][v];
    *reinterpret_cast<bf16x4*>(row + k * Cin + sub * 4) = tmp;
  }
  *reinterpret_cast<bf16x4*>(row + 9 * Cin + sub * 4) = xd;
  __syncthreads();

  int lane = t & 63, wave = t >> 6;
  int c15 = lane & 15, q = lane >> 4;
  for (int u = wave; u < UNITS; u += 4) {
    int tile = u / CT, ct = u - tile * CT;
    const __bf16* arow = As + (size_t)(tile * 16 + c15) * KP2 + q * 8;
    f32x4 a4 = {0.f, 0.f, 0.f, 0.f};
    #pragma unroll
    for (int kc = 0; kc < KC; ++kc) {
      bf16x8 a = *reinterpret_cast<const bf16x8*>(arow + kc * 32);
      bf16x8 b = *reinterpret_cast<const bf16x8*>(Bp + ((size_t)(kc * CT + ct) * 64 + lane) * 8);
      a4 = __builtin_amdgcn_mfma_f32_16x16x32_bf16(a, b, a4, 0, 0, 0);
    }
    int cout = ct * 16 + c15;
    float bb = bias[cout];
    #pragma unroll
    for (int r = 0; r < 4; ++r) {
      int m = q * 4 + r;
      int dd = blockIdx.x * DPB + tile * 16 + m;
      if (dd < N) {
        float vv = fmaxf(a4[r] + bb, 0.f);
        if constexpr (OUTF32)
          ((float*)outv)[(size_t)dd * outStride + cout] = vv;
        else
          ((__bf16*)outv)[(size_t)dd * outStride + cout] = (__bf16)vv;
        if constexpr (HAS_SKIP) {
          float sv = skip[(size_t)dd * Cout + cout];
          ((__bf16*)outv)[(size_t)dd * outStride + Cout + cout] = (__bf16)sv;
        }
      }
    }
  }
}

extern "C" void kernel_launch(void* const* d_in, const int* in_sizes, int n_in,
                              void* d_out, int out_size, void* d_ws, size_t ws_size,
                              hipStream_t stream) {
  const float* x0      = (const float*)d_in[0];
  const int*   up1     = (const int*)d_in[1];
  const int*   edge1   = (const int*)d_in[2];
  const float* pseudo1 = (const float*)d_in[3];
  const float* skip1   = (const float*)d_in[4];
  const int*   up2     = (const int*)d_in[5];
  const int*   edge2   = (const int*)d_in[6];
  const float* pseudo2 = (const float*)d_in[7];
  const float* skip2   = (const float*)d_in[8];
  const float* W1a = (const float*)d_in[9];
  const float* R1a = (const float*)d_in[10];
  const float* b1a = (const float*)d_in[11];
  const float* W2a = (const float*)d_in[12];
  const float* R2a = (const float*)d_in[13];
  const float* b2a = (const float*)d_in[14];
  const float* W1b = (const float*)d_in[15];
  const float* R1b = (const float*)d_in[16];
  const float* b1b = (const float*)d_in[17];
  const float* W2b = (const float*)d_in[18];
  const float* R2b = (const float*)d_in[19];
  const float* b2b = (const float*)d_in[20];

  const int N1 = 40000, N2 = 160000, E1 = 240000, E2 = 960000;
  const int NBK1 = (N1 + 1023) / 1024;  // 40
  const int NBK2 = (N2 + 1023) / 1024;  // 157

  char* ws = (char*)d_ws;
  __bf16* x1    = (__bf16*)(ws);               // [N1,64]  5,120,000 B
  __bf16* xcat1 = (__bf16*)(ws +  5120000);    // [N1,64]  5,120,000
  __bf16* x3    = (__bf16*)(ws + 10240000);    // [N1,32]  2,560,000
  __bf16* h1    = (__bf16*)(ws + 12800000);    // [N1,32]  2,560,000
  __bf16* x2    = (__bf16*)(ws + 15360000);    // [N2,32] 10,240,000
  __bf16* xcat2 = (__bf16*)(ws + 25600000);    // [N2,32] 10,240,000
  __bf16* x6    = (__bf16*)(ws + 35840000);    // [N2,16]  5,120,000
  int* off    = (int*)(ws + 40960000);         // (N2+1)*4
  uint2* ebuf = (uint2*)(ws + 41600016);       // E2*8
  uint2* epk  = (uint2*)(ws + 49280016);       // E2*8
  int* bcnt   = (int*)(ws + 56960016);         // 1,024
  int* bstart = (int*)(ws + 56961040);         // 1,040
  int* bcur   = (int*)(ws + 56962080);         // 1,024
  __bf16* BpA = (__bf16*)(ws + 56963104);      // 40,960
  __bf16* BpB = (__bf16*)(ws + 57004064);      // 20,480
  __bf16* BpC = (__bf16*)(ws + 57024544);      // 10,240
  __bf16* BpD = (__bf16*)(ws + 57034784);      //  5,120

  k_packall<<<150, 256, 0, stream>>>(W1a, R1a, W2a, R2a, W1b, R1b, W2b, R2b,
                                     BpA, BpB, BpC, BpD);

  // ---------------- level 1 ----------------
  k_up_f2b<<<N1 * 16 / 256, 256, 0, stream>>>((const float4*)x0, up1, x1, N1, 16, 64);

  hipMemsetAsync(bcnt, 0, 256 * 4, stream);
  k_bhist<<<(E1 + 2047) / 2048, 256, 0, stream>>>(edge1 + E1, E1, bcnt, NBK1);
  k_bscan<<<1, 256, 0, stream>>>(bcnt, NBK1, E1, bstart, bcur);
  k_bpart<<<(E1 + 2047) / 2048, 256, 0, stream>>>(edge1, edge1 + E1, (const float2*)pseudo1,
                                                  E1, bcur, ebuf, NBK1);
  k_bcsr<<<NBK1, 256, 0, stream>>>(bstart, ebuf, epk, off, N1, E1, NBK1);

  // conv1a: x1(64) -> xcat1[:, :32]; skip1 fused into cols [32,64)
  k_conv<64, 32, false, true><<<N1 / 16, 256, 0, stream>>>(off, epk, x1, BpA, b1a, skip1, xcat1, N1, 64);
  // conv2a: xcat1(64) -> x3(32)
  k_conv<64, 32, false, false><<<N1 / 16, 256, 0, stream>>>(off, epk, xcat1, BpA, b1a, nullptr, x3, N1, 32);
  // conv3a: x3(32) -> h1(32)
  k_conv<32, 32, false, false><<<N1 / 32, 256, 0, stream>>>(off, epk, x3, BpB, b2a, nullptr, h1, N1, 32);

  // ---------------- level 2 ----------------
  k_up_b2b<<<N2 * 4 / 256, 256, 0, stream>>>((const uint4*)h1, up2, (uint4*)x2, N2, 4);

  hipMemsetAsync(bcnt, 0, 256 * 4, stream);
  k_bhist<<<(E2 + 2047) / 2048, 256, 0, stream>>>(edge2 + E2, E2, bcnt, NBK2);
  k_bscan<<<1, 256, 0, stream>>>(bcnt, NBK2, E2, bstart, bcur);
  k_bpart<<<(E2 + 2047) / 2048, 256, 0, stream>>>(edge2, edge2 + E2, (const float2*)pseudo2,
                                                  E2, bcur, ebuf, NBK2);
  k_bcsr<<<NBK2, 256, 0, stream>>>(bstart, ebuf, epk, off, N2, E2, NBK2);

  // conv1b: x2(32) -> xcat2[:, :16]; skip2 fused into cols [16,32)
  k_conv<32, 16, false, true><<<N2 / 32, 256, 0, stream>>>(off, epk, x2, BpC, b1b, skip2, xcat2, N2, 32);
  // conv2b: xcat2(32) -> x6(16)
  k_conv<32, 16, false, false><<<N2 / 32, 256, 0, stream>>>(off, epk, xcat2, BpC, b1b, nullptr, x6, N2, 16);
  // conv3b: x6(16) -> out(16) fp32
  k_conv<16, 16, true, false><<<N2 / 64, 256, 0, stream>>>(off, epk, x6, BpD, b2b, nullptr, d_out, N2, 16);
}

// Round 11
// 313.535 us; speedup vs baseline: 1.1392x; 1.1392x over previous
//
#include <hip/hip_runtime.h>
#include <stdint.h>

typedef __bf16 bf16x8 __attribute__((ext_vector_type(8)));
typedef __bf16 bf16x4 __attribute__((ext_vector_type(4)));
typedef float  f32x4  __attribute__((ext_vector_type(4)));

// ---------------- standalone unpool (bf16 rows gathered), used between levels --------
__global__ void k_up_b2b(const uint4* __restrict__ xin, const int* __restrict__ up,
                         uint4* __restrict__ xout, int N, int rowU4) {
  int i = blockIdx.x * 256 + threadIdx.x;
  if (i >= N * rowU4) return;
  int n = i / rowU4, j = i - n * rowU4;
  xout[i] = xin[(size_t)up[n] * rowU4 + j];
}

// ================== fused prologue: packall + up_f2b + bhist(L1) + bhist(L2) ==========
// block ranges: [0,150) pack, [150,2650) up_f2b, [2650,2768) bhist1, [2768,3237) bhist2
__device__ __forceinline__ void d_pack(int o,
    const float* W1a, const float* R1a, const float* W2a, const float* R2a,
    const float* W1b, const float* R1b, const float* W2b, const float* R2b,
    __bf16* BpA, __bf16* BpB, __bf16* BpC, __bf16* BpD) {
  const float *W, *R; __bf16* Bp; int Cin, Cout;
  if (o < 20480)      { W = W1a; R = R1a; Bp = BpA; Cin = 64; Cout = 32; }
  else if (o < 30720) { W = W2a; R = R2a; Bp = BpB; Cin = 32; Cout = 32; o -= 20480; }
  else if (o < 35840) { W = W1b; R = R1b; Bp = BpC; Cin = 32; Cout = 16; o -= 30720; }
  else if (o < 38400) { W = W2b; R = R2b; Bp = BpD; Cin = 16; Cout = 16; o -= 35840; }
  else return;
  int CT = Cout / 16;
  int j = o & 7, lane = (o >> 3) & 63, tile = o >> 9;
  int ct = tile % CT, kc = tile / CT;
  int k = kc * 32 + ((lane >> 4) * 8) + j;
  int n = ct * 16 + (lane & 15);
  float v;
  if (k < 9 * Cin) { int k9 = k / Cin, cin = k - k9 * Cin; v = W[(k9 * Cin + cin) * Cout + n]; }
  else             { v = R[(k - 9 * Cin) * Cout + n]; }
  Bp[o] = (__bf16)v;
}

__device__ __forceinline__ void d_bhist(int b, int t, const int* dst, int E,
                                        int* bcnt, int nbk) {
  __shared__ int h[256];
  h[t] = 0;
  __syncthreads();
  int e0 = b * 2048 + t * 8;
  if (e0 + 8 <= E) {
    int4 a = *reinterpret_cast<const int4*>(dst + e0);
    int4 c = *reinterpret_cast<const int4*>(dst + e0 + 4);
    atomicAdd(&h[a.x >> 10], 1); atomicAdd(&h[a.y >> 10], 1);
    atomicAdd(&h[a.z >> 10], 1); atomicAdd(&h[a.w >> 10], 1);
    atomicAdd(&h[c.x >> 10], 1); atomicAdd(&h[c.y >> 10], 1);
    atomicAdd(&h[c.z >> 10], 1); atomicAdd(&h[c.w >> 10], 1);
  } else {
    for (int j = 0; j < 8; ++j)
      if (e0 + j < E) atomicAdd(&h[dst[e0 + j] >> 10], 1);
  }
  __syncthreads();
  if (t < nbk && h[t]) atomicAdd(&bcnt[t], h[t]);
}

__global__ __launch_bounds__(256) void k_prologue(
    const float* __restrict__ W1a, const float* __restrict__ R1a,
    const float* __restrict__ W2a, const float* __restrict__ R2a,
    const float* __restrict__ W1b, const float* __restrict__ R1b,
    const float* __restrict__ W2b, const float* __restrict__ R2b,
    __bf16* __restrict__ BpA, __bf16* __restrict__ BpB,
    __bf16* __restrict__ BpC, __bf16* __restrict__ BpD,
    const float4* __restrict__ x0, const int* __restrict__ up1, __bf16* __restrict__ x1,
    const int* __restrict__ dst1, int E1, int* __restrict__ bcnt1, int nbk1,
    const int* __restrict__ dst2, int E2, int* __restrict__ bcnt2, int nbk2,
    int N1) {
  int b = blockIdx.x, t = threadIdx.x;
  if (b < 150) {
    d_pack(b * 256 + t, W1a, R1a, W2a, R2a, W1b, R1b, W2b, R2b, BpA, BpB, BpC, BpD);
  } else if (b < 2650) {
    int i = (b - 150) * 256 + t;            // N1*16 = 640,000 items
    if (i < N1 * 16) {
      int n = i >> 4, j = i & 15;
      float4 v = x0[(size_t)up1[n] * 16 + j];
      bf16x4 o = {(__bf16)v.x, (__bf16)v.y, (__bf16)v.z, (__bf16)v.w};
      *reinterpret_cast<bf16x4*>(x1 + (size_t)n * 64 + j * 4) = o;
    }
  } else if (b < 2768) {
    d_bhist(b - 2650, t, dst1, E1, bcnt1, nbk1);
  } else {
    d_bhist(b - 2768, t, dst2, E2, bcnt2, nbk2);
  }
}

// ---------------- dual bucket scan: block 0 = L1, block 1 = L2 ----------------
__global__ void k_bscan_dual(const int* __restrict__ bcnt1, int nbk1, int E1,
                             int* __restrict__ bstart1, int* __restrict__ bcur1,
                             const int* __restrict__ bcnt2, int nbk2, int E2,
                             int* __restrict__ bstart2, int* __restrict__ bcur2) {
  const int* bcnt; int nbk, E; int *bstart, *bcur;
  if (blockIdx.x == 0) { bcnt = bcnt1; nbk = nbk1; E = E1; bstart = bstart1; bcur = bcur1; }
  else                 { bcnt = bcnt2; nbk = nbk2; E = E2; bstart = bstart2; bcur = bcur2; }
  __shared__ int wsum[4];
  int t = threadIdx.x, lane = t & 63, w = t >> 6;
  int v = (t < nbk) ? bcnt[t] : 0;
  int x = v;
  #pragma unroll
  for (int o = 1; o < 64; o <<= 1) { int y = __shfl_up(x, o, 64); if (lane >= o) x += y; }
  if (lane == 63) wsum[w] = x;
  __syncthreads();
  int wpre = 0;
  #pragma unroll
  for (int k = 0; k < 4; ++k) if (k < w) wpre += wsum[k];
  int excl = wpre + x - v;
  if (t < nbk) { bstart[t] = excl; bcur[t] = excl; }
  if (t == 0) bstart[nbk] = E;
}

// ---------------- dual partition: blocks [0,118) L1, [118,587) L2 ----------------
__device__ __forceinline__ void d_bpart(int b, int t, const int* src, const int* dst,
                                        const float2* pse, int E, int* bcur,
                                        uint2* ebuf, int nbk) {
  __shared__ int h[256];
  __shared__ int base[256];
  h[t] = 0;
  __syncthreads();
  int e0 = b * 2048 + t * 8;
  int d[8], rank[8];
  bool full = (e0 + 8 <= E);
  if (full) {
    int4 a = *reinterpret_cast<const int4*>(dst + e0);
    int4 c = *reinterpret_cast<const int4*>(dst + e0 + 4);
    d[0] = a.x; d[1] = a.y; d[2] = a.z; d[3] = a.w;
    d[4] = c.x; d[5] = c.y; d[6] = c.z; d[7] = c.w;
    #pragma unroll
    for (int j = 0; j < 8; ++j) rank[j] = atomicAdd(&h[d[j] >> 10], 1);
  } else {
    #pragma unroll
    for (int j = 0; j < 8; ++j)
      if (e0 + j < E) { d[j] = dst[e0 + j]; rank[j] = atomicAdd(&h[d[j] >> 10], 1); }
  }
  __syncthreads();
  if (t < nbk && h[t]) base[t] = atomicAdd(&bcur[t], h[t]);
  __syncthreads();
  if (full) {
    int4 a = *reinterpret_cast<const int4*>(src + e0);
    int4 c = *reinterpret_cast<const int4*>(src + e0 + 4);
    int s[8] = {a.x, a.y, a.z, a.w, c.x, c.y, c.z, c.w};
    float2 p[8];
    #pragma unroll
    for (int j = 0; j < 8; ++j) p[j] = pse[e0 + j];
    #pragma unroll
    for (int j = 0; j < 8; ++j) {
      int bkt = d[j] >> 10, dloc = d[j] & 1023;
      union { uint u; _Float16 hh[2]; } cv;
      cv.hh[0] = (_Float16)p[j].x; cv.hh[1] = (_Float16)p[j].y;
      ebuf[base[bkt] + rank[j]] = make_uint2((uint)s[j] | ((uint)dloc << 18), cv.u);
    }
  } else {
    #pragma unroll
    for (int j = 0; j < 8; ++j) {
      if (e0 + j >= E) continue;
      int bkt = d[j] >> 10, dloc = d[j] & 1023;
      float2 p = pse[e0 + j];
      union { uint u; _Float16 hh[2]; } cv;
      cv.hh[0] = (_Float16)p.x; cv.hh[1] = (_Float16)p.y;
      ebuf[base[bkt] + rank[j]] = make_uint2((uint)src[e0 + j] | ((uint)dloc << 18), cv.u);
    }
  }
}

__global__ __launch_bounds__(256) void k_bpart_dual(
    const int* __restrict__ src1, const int* __restrict__ dst1, const float2* __restrict__ pse1,
    int E1, int* __restrict__ bcur1, uint2* __restrict__ ebuf1, int nbk1, int NB1,
    const int* __restrict__ src2, const int* __restrict__ dst2, const float2* __restrict__ pse2,
    int E2, int* __restrict__ bcur2, uint2* __restrict__ ebuf2, int nbk2) {
  int b = blockIdx.x, t = threadIdx.x;
  if (b < NB1) d_bpart(b, t, src1, dst1, pse1, E1, bcur1, ebuf1, nbk1);
  else         d_bpart(b - NB1, t, src2, dst2, pse2, E2, bcur2, ebuf2, nbk2);
}

// ---------------- dual per-bucket CSR finalize: blocks [0,40) L1, [40,197) L2 ----------
__device__ __forceinline__ void d_bcsr(int b, int t, const int* bstart, const uint2* ebuf,
                                       uint2* epk, int* off, int N, int E, int nbk) {
  __shared__ int cnt[1024];
  __shared__ int excl[1024];
  __shared__ int cur[1024];
  __shared__ int wsum[4];
  int e0 = bstart[b], e1 = bstart[b + 1];
  #pragma unroll
  for (int k = 0; k < 4; ++k) { cnt[t * 4 + k] = 0; cur[t * 4 + k] = 0; }
  __syncthreads();
  for (int i = e0 + t; i < e1; i += 256)
    atomicAdd(&cnt[(ebuf[i].x >> 18) & 1023], 1);
  __syncthreads();
  int lane = t & 63, w = t >> 6;
  int i0 = t * 4;
  int c0 = cnt[i0], c1 = cnt[i0 + 1], c2 = cnt[i0 + 2], c3 = cnt[i0 + 3];
  int s = c0 + c1 + c2 + c3, x = s;
  #pragma unroll
  for (int o = 1; o < 64; o <<= 1) { int y = __shfl_up(x, o, 64); if (lane >= o) x += y; }
  if (lane == 63) wsum[w] = x;
  __syncthreads();
  int wpre = 0;
  #pragma unroll
  for (int k = 0; k < 4; ++k) if (k < w) wpre += wsum[k];
  int ex = wpre + x - s;
  excl[i0] = ex; excl[i0 + 1] = ex + c0; excl[i0 + 2] = ex + c0 + c1; excl[i0 + 3] = ex + c0 + c1 + c2;
  int dg0 = b * 1024;
  int exv[4] = {ex, ex + c0, ex + c0 + c1, ex + c0 + c1 + c2};
  #pragma unroll
  for (int k = 0; k < 4; ++k) {
    int d = dg0 + i0 + k;
    if (d < N) off[d] = e0 + exv[k];
  }
  __syncthreads();
  for (int i = e0 + t; i < e1; i += 256) {
    uint2 r = ebuf[i];
    int dloc = (r.x >> 18) & 1023;
    int rk = atomicAdd(&cur[dloc], 1);
    epk[e0 + excl[dloc] + rk] = make_uint2(r.x & 0x3FFFFu, r.y);
  }
  if (b == nbk - 1 && t == 0) off[N] = E;
}

__global__ __launch_bounds__(256) void k_bcsr_dual(
    const int* __restrict__ bstart1, const uint2* __restrict__ ebuf1, uint2* __restrict__ epk1,
    int* __restrict__ off1, int N1, int E1, int nbk1,
    const int* __restrict__ bstart2, const uint2* __restrict__ ebuf2, uint2* __restrict__ epk2,
    int* __restrict__ off2, int N2, int E2, int nbk2) {
  int b = blockIdx.x, t = threadIdx.x;
  if (b < nbk1) d_bcsr(b, t, bstart1, ebuf1, epk1, off1, N1, E1, nbk1);
  else          d_bcsr(b - nbk1, t, bstart2, ebuf2, epk2, off2, N2, E2, nbk2);
}

// -------- fused spline conv: chunk-4 prefetched edge loop -> LDS -> MFMA -----
// (256,4): <=128 VGPR, no spill of the chunk-4 state (R10's (256,6) regressed: spills).
template<int Cin, int Cout, bool OUTF32, bool HAS_SKIP>
__global__ __launch_bounds__(256, 4) void k_conv(const int* __restrict__ off,
                        const uint2* __restrict__ epk,
                        const __bf16* __restrict__ X, const __bf16* __restrict__ Bp,
                        const float* __restrict__ bias, const float* __restrict__ skip,
                        void* __restrict__ outv, int N, int outStride) {
  constexpr int LPD = Cin / 4;      // lanes per dst: 4/8/16
  constexpr int DPB = 256 / LPD;    // dsts per block: 64/32/16
  constexpr int K   = 10 * Cin;     // 160/320/640
  constexpr int KP2 = K + 8;        // LDS row stride
  constexpr int NT  = DPB / 16;     // MFMA row-tiles per block
  constexpr int KC  = K / 32;
  constexpr int CT  = Cout / 16;
  constexpr int UNITS = NT * CT;

  __shared__ __bf16 As[DPB * KP2];

  int t = threadIdx.x;
  int g = t / LPD, sub = t % LPD;
  int d = blockIdx.x * DPB + g;

  float acc[9][4];
  #pragma unroll
  for (int k = 0; k < 9; ++k)
    #pragma unroll
    for (int v = 0; v < 4; ++v) acc[k][v] = 0.f;
  bf16x4 xd = {};

  if (d < N) {
    xd = *reinterpret_cast<const bf16x4*>(X + (size_t)d * Cin + sub * 4);
    int b0 = off[d], b1 = off[d + 1];
    int i = b0;
    for (; i + 4 <= b1; i += 4) {
      uint2 e0 = epk[i], e1 = epk[i + 1], e2 = epk[i + 2], e3 = epk[i + 3];
      bf16x4 xf0 = *reinterpret_cast<const bf16x4*>(X + (size_t)e0.x * Cin + sub * 4);
      bf16x4 xf1 = *reinterpret_cast<const bf16x4*>(X + (size_t)e1.x * Cin + sub * 4);
      bf16x4 xf2 = *reinterpret_cast<const bf16x4*>(X + (size_t)e2.x * Cin + sub * 4);
      bf16x4 xf3 = *reinterpret_cast<const bf16x4*>(X + (size_t)e3.x * Cin + sub * 4);
      uint ps[4] = {e0.y, e1.y, e2.y, e3.y};
      bf16x4 xfs[4] = {xf0, xf1, xf2, xf3};
      #pragma unroll
      for (int c = 0; c < 4; ++c) {
        union { uint u; _Float16 h[2]; } cv; cv.u = ps[c];
        float t0 = (float)cv.h[0], t1 = (float)cv.h[1];
        float u0 = 1.f - t0;
        float wi[3] = {0.5f * u0 * u0, -t0 * t0 + t0 + 0.5f, 0.5f * t0 * t0};
        float u1 = 1.f - t1;
        float wj[3] = {0.5f * u1 * u1, -t1 * t1 + t1 + 0.5f, 0.5f * t1 * t1};
        float xfv[4];
        #pragma unroll
        for (int v = 0; v < 4; ++v) xfv[v] = (float)xfs[c][v];
        #pragma unroll
        for (int ki = 0; ki < 3; ++ki)
          #pragma unroll
          for (int kj = 0; kj < 3; ++kj) {
            float w = wi[ki] * wj[kj];
            #pragma unroll
            for (int v = 0; v < 4; ++v)
              acc[ki * 3 + kj][v] += w * xfv[v];
          }
      }
    }
    for (; i < b1; ++i) {
      uint2 ep = epk[i];
      bf16x4 xf = *reinterpret_cast<const bf16x4*>(X + (size_t)ep.x * Cin + sub * 4);
      union { uint u; _Float16 h[2]; } cv; cv.u = ep.y;
      float t0 = (float)cv.h[0], t1 = (float)cv.h[1];
      float u0 = 1.f - t0;
      float wi[3] = {0.5f * u0 * u0, -t0 * t0 + t0 + 0.5f, 0.5f * t0 * t0};
      float u1 = 1.f - t1;
      float wj[3] = {0.5f * u1 * u1, -t1 * t1 + t1 + 0.5f, 0.5f * t1 * t1};
      float xfv[4];
      #pragma unroll
      for (int v = 0; v < 4; ++v) xfv[v] = (float)xf[v];
      #pragma unroll
      for (int ki = 0; ki < 3; ++ki)
        #pragma unroll
        for (int kj = 0; kj < 3; ++kj) {
          float w = wi[ki] * wj[kj];
          #pragma unroll
          for (int v = 0; v < 4; ++v)
            acc[ki * 3 + kj][v] += w * xfv[v];
        }
    }
  }

  __bf16* row = As + (size_t)g * KP2;
  #pragma unroll
  for (int k = 0; k < 9; ++k) {
    bf16x4 tmp;
    #pragma unroll
    for (int v = 0; v < 4; ++v) tmp[v] = (__bf16)acc[k][v];
    *reinterpret_cast<bf16x4*>(row + k * Cin + sub * 4) = tmp;
  }
  *reinterpret_cast<bf16x4*>(row + 9 * Cin + sub * 4) = xd;
  __syncthreads();

  int lane = t & 63, wave = t >> 6;
  int c15 = lane & 15, q = lane >> 4;
  for (int u = wave; u < UNITS; u += 4) {
    int tile = u / CT, ct = u - tile * CT;
    const __bf16* arow = As + (size_t)(tile * 16 + c15) * KP2 + q * 8;
    f32x4 a4 = {0.f, 0.f, 0.f, 0.f};
    #pragma unroll
    for (int kc = 0; kc < KC; ++kc) {
      bf16x8 a = *reinterpret_cast<const bf16x8*>(arow + kc * 32);
      bf16x8 b = *reinterpret_cast<const bf16x8*>(Bp + ((size_t)(kc * CT + ct) * 64 + lane) * 8);
      a4 = __builtin_amdgcn_mfma_f32_16x16x32_bf16(a, b, a4, 0, 0, 0);
    }
    int cout = ct * 16 + c15;
    float bb = bias[cout];
    #pragma unroll
    for (int r = 0; r < 4; ++r) {
      int m = q * 4 + r;
      int dd = blockIdx.x * DPB + tile * 16 + m;
      if (dd < N) {
        float vv = fmaxf(a4[r] + bb, 0.f);
        if constexpr (OUTF32)
          ((float*)outv)[(size_t)dd * outStride + cout] = vv;
        else
          ((__bf16*)outv)[(size_t)dd * outStride + cout] = (__bf16)vv;
        if constexpr (HAS_SKIP) {
          float sv = skip[(size_t)dd * Cout + cout];
          ((__bf16*)outv)[(size_t)dd * outStride + Cout + cout] = (__bf16)sv;
        }
      }
    }
  }
}

extern "C" void kernel_launch(void* const* d_in, const int* in_sizes, int n_in,
                              void* d_out, int out_size, void* d_ws, size_t ws_size,
                              hipStream_t stream) {
  const float* x0      = (const float*)d_in[0];
  const int*   up1     = (const int*)d_in[1];
  const int*   edge1   = (const int*)d_in[2];
  const float* pseudo1 = (const float*)d_in[3];
  const float* skip1   = (const float*)d_in[4];
  const int*   up2     = (const int*)d_in[5];
  const int*   edge2   = (const int*)d_in[6];
  const float* pseudo2 = (const float*)d_in[7];
  const float* skip2   = (const float*)d_in[8];
  const float* W1a = (const float*)d_in[9];
  const float* R1a = (const float*)d_in[10];
  const float* b1a = (const float*)d_in[11];
  const float* W2a = (const float*)d_in[12];
  const float* R2a = (const float*)d_in[13];
  const float* b2a = (const float*)d_in[14];
  const float* W1b = (const float*)d_in[15];
  const float* R1b = (const float*)d_in[16];
  const float* b1b = (const float*)d_in[17];
  const float* W2b = (const float*)d_in[18];
  const float* R2b = (const float*)d_in[19];
  const float* b2b = (const float*)d_in[20];

  const int N1 = 40000, N2 = 160000, E1 = 240000, E2 = 960000;
  const int NBK1 = 40, NBK2 = 157;
  const int NB1 = (E1 + 2047) / 2048;   // 118
  const int NB2 = (E2 + 2047) / 2048;   // 469

  char* ws = (char*)d_ws;
  __bf16* x1     = (__bf16*)(ws);                // [N1,64]  5,120,000
  __bf16* xcat1  = (__bf16*)(ws +  5120000);     // [N1,64]  5,120,000
  __bf16* x3     = (__bf16*)(ws + 10240000);     // [N1,32]  2,560,000
  __bf16* h1     = (__bf16*)(ws + 12800000);     // [N1,32]  2,560,000
  __bf16* x2     = (__bf16*)(ws + 15360000);     // [N2,32] 10,240,000
  __bf16* xcat2  = (__bf16*)(ws + 25600000);     // [N2,32] 10,240,000
  __bf16* x6     = (__bf16*)(ws + 35840000);     // [N2,16]  5,120,000
  int*   off1    = (int*)(ws + 40960000);        // (N1+1)*4 -> pad 160,016
  uint2* ebuf1   = (uint2*)(ws + 41120016);      // E1*8 = 1,920,000
  uint2* epk1    = (uint2*)(ws + 43040016);      // 1,920,000
  int*   off2    = (int*)(ws + 44960016);        // (N2+1)*4 -> pad 640,016
  uint2* ebuf2   = (uint2*)(ws + 45600032);      // E2*8 = 7,680,000
  uint2* epk2    = (uint2*)(ws + 53280032);      // 7,680,000
  int*   bcnt12  = (int*)(ws + 60960032);        // 512*4 (bcnt1 = +0, bcnt2 = +256)
  int*   bstart1 = (int*)(ws + 60962080);        // 256 B
  int*   bcur1   = (int*)(ws + 60962336);        // 256 B
  int*   bstart2 = (int*)(ws + 60962592);        // 1,024 B
  int*   bcur2   = (int*)(ws + 60963616);        // 1,024 B
  __bf16* BpA    = (__bf16*)(ws + 60964640);     // 40,960
  __bf16* BpB    = (__bf16*)(ws + 61005600);     // 20,480
  __bf16* BpC    = (__bf16*)(ws + 61026080);     // 10,240
  __bf16* BpD    = (__bf16*)(ws + 61036320);     //  5,120
  int* bcnt1 = bcnt12, *bcnt2 = bcnt12 + 256;

  // 1: zero both bucket-count arrays in one call
  hipMemsetAsync(bcnt12, 0, 512 * 4, stream);

  // 2: fused prologue (weight pack + level-1 unpool/cvt + both bucket histograms)
  k_prologue<<<150 + 2500 + NB1 + NB2, 256, 0, stream>>>(
      W1a, R1a, W2a, R2a, W1b, R1b, W2b, R2b, BpA, BpB, BpC, BpD,
      (const float4*)x0, up1, x1,
      edge1 + E1, E1, bcnt1, NBK1,
      edge2 + E2, E2, bcnt2, NBK2, N1);

  // 3: dual bucket scan
  k_bscan_dual<<<2, 256, 0, stream>>>(bcnt1, NBK1, E1, bstart1, bcur1,
                                      bcnt2, NBK2, E2, bstart2, bcur2);

  // 4: dual partition
  k_bpart_dual<<<NB1 + NB2, 256, 0, stream>>>(
      edge1, edge1 + E1, (const float2*)pseudo1, E1, bcur1, ebuf1, NBK1, NB1,
      edge2, edge2 + E2, (const float2*)pseudo2, E2, bcur2, ebuf2, NBK2);

  // 5: dual per-bucket CSR finalize
  k_bcsr_dual<<<NBK1 + NBK2, 256, 0, stream>>>(
      bstart1, ebuf1, epk1, off1, N1, E1, NBK1,
      bstart2, ebuf2, epk2, off2, N2, E2, NBK2);

  // ---------------- level 1 convs ----------------
  k_conv<64, 32, false, true><<<N1 / 16, 256, 0, stream>>>(off1, epk1, x1, BpA, b1a, skip1, xcat1, N1, 64);
  k_conv<64, 32, false, false><<<N1 / 16, 256, 0, stream>>>(off1, epk1, xcat1, BpA, b1a, nullptr, x3, N1, 32);
  k_conv<32, 32, false, false><<<N1 / 32, 256, 0, stream>>>(off1, epk1, x3, BpB, b2a, nullptr, h1, N1, 32);

  // unpool h1 -> x2
  k_up_b2b<<<N2 * 4 / 256, 256, 0, stream>>>((const uint4*)h1, up2, (uint4*)x2, N2, 4);

  // ---------------- level 2 convs ----------------
  k_conv<32, 16, false, true><<<N2 / 32, 256, 0, stream>>>(off2, epk2, x2, BpC, b1b, skip2, xcat2, N2, 32);
  k_conv<32, 16, false, false><<<N2 / 32, 256, 0, stream>>>(off2, epk2, xcat2, BpC, b1b, nullptr, x6, N2, 16);
  k_conv<16, 16, true, false><<<N2 / 64, 256, 0, stream>>>(off2, epk2, x6, BpD, b2b, nullptr, d_out, N2, 16);
}